// Round 15
// baseline (2218.408 us; speedup 1.0000x reference)
//
#include <hip/hip_runtime.h>
#include <hip/hip_bf16.h>
#include <hip/hip_cooperative_groups.h>

namespace cg = cooperative_groups;

#define ND 128
#define ED 128
#define NIN 128
#define EIN 291
#define KPAD 320   // EIN padded to multiple of 32 (w0eT row stride)
#define HH 64
#define TM 32      // nodes per block in node-embed / edges per block in classify
#define TS 64      // edges per block in edge_step
#define GSE 768    // grid blocks for edge_embed part (3 per CU)
#define MAXGE 3    // max 64-edge tiles per edge_embed block
#define CGRID 1024 // cooperative grid: 4 blocks/CU x 256 CU

typedef __attribute__((ext_vector_type(8))) short short8;
typedef __attribute__((ext_vector_type(4))) float float4_;

__device__ __forceinline__ unsigned short f2bf(float f)
{
    union { float f; unsigned u; } v; v.f = f;
    unsigned u = v.u;
    unsigned r = (u + 0x7FFFu + ((u >> 16) & 1u)) >> 16;  // RNE
    return (unsigned short)r;
}
__device__ __forceinline__ float bf2f(unsigned short s)
{
    union { unsigned u; float f; } v; v.u = ((unsigned)s) << 16;
    return v.f;
}

// Stage T N-tiles x KC k-chunks of B (layout [col][K], bf16) into LDS in MFMA
// FRAGMENT ORDER: fragment f=tt*KC+kc occupies 64 consecutive short8 slots.
template<int T, int KC, int K>
__device__ __forceinline__ void stage_frags(const unsigned short* __restrict__ src,
                                            unsigned short* __restrict__ wreg,
                                            int t, int k0)
{
    constexpr int TOT = T * KC * 64;
#pragma unroll
    for (int it = 0; it < TOT / 256; it++) {
        int idx = it * 256 + t;
        int f = idx >> 6, l = idx & 63;
        int col = (f / KC) * 16 + (l & 15);
        int k = (f % KC) * 32 + ((l >> 4) * 8);
        *(short8*)&wreg[idx * 8] = *(const short8*)&src[(size_t)col * K + k0 + k];
    }
}
#define FRAG(wreg, f, lane) (*(const short8*)&(wreg)[(((f) << 6) + (lane)) * 8])

// ---- CSR build (once per launch; edge_index is constant across the 4 steps) ----
__global__ __launch_bounds__(256) void hist_k(const int* __restrict__ tgti,
                                              int* __restrict__ deg, int E)
{
    int e = blockIdx.x * 256 + threadIdx.x;
    if (e < E) atomicAdd(&deg[tgti[e]], 1);
}

// Single-block exclusive scan over deg[0..N) -> row_ptr & cursor.
__global__ __launch_bounds__(256) void scan_k(const int* __restrict__ deg,
                                              int* __restrict__ row_ptr,
                                              int* __restrict__ cursor, int N, int E)
{
    __shared__ int part[256];
    const int t = threadIdx.x;
    const int chunk = (N + 255) / 256;
    const int base = t * chunk;
    int s = 0;
    for (int k = 0; k < chunk; k++) { int idx = base + k; if (idx < N) s += deg[idx]; }
    part[t] = s;
    __syncthreads();
    for (int off = 1; off < 256; off <<= 1) {
        int v = (t >= off) ? part[t - off] : 0;
        __syncthreads();
        part[t] += v;
        __syncthreads();
    }
    int run = (t == 0) ? 0 : part[t - 1];
    for (int k = 0; k < chunk; k++) {
        int idx = base + k;
        if (idx < N) { row_ptr[idx] = run; cursor[idx] = run; run += deg[idx]; }
    }
    if (t == 255) row_ptr[N] = E;
}

// scatter + positional perm fused: writes csr_eid, srcp, tgtp in one pass.
__global__ __launch_bounds__(256) void scatter_k(const int* __restrict__ srcj,
                                                 const int* __restrict__ tgti,
                                                 int* __restrict__ cursor,
                                                 int* __restrict__ csr_eid,
                                                 int* __restrict__ srcp,
                                                 int* __restrict__ tgtp, int E)
{
    int e = blockIdx.x * 256 + threadIdx.x;
    if (e < E) {
        int tg = tgti[e];
        int p = atomicAdd(&cursor[tg], 1);
        csr_eid[p] = e;
        srcp[p] = srcj[e];
        tgtp[p] = tg;
    }
}

// Boundary fixup (fallback path only).
__global__ __launch_bounds__(256) void fixup_k(const int* __restrict__ row_ptr,
                                               float* __restrict__ nfx,
                                               unsigned short* __restrict__ nf_out, int N)
{
    int n = blockIdx.x * 2 + (threadIdx.x >> 7);
    int c = threadIdx.x & 127;
    if (n >= N) return;
    int beg = row_ptr[n], end = row_ptr[n + 1];
    if (beg == end) { nf_out[(size_t)n * ND + c] = 0; return; }
    if ((beg >> 5) != ((end - 1) >> 5)) {
        size_t idx = (size_t)n * ND + c;
        nf_out[idx] = f2bf(nfx[idx]);
        nfx[idx] = 0.f;
    }
}

// One-time weight prep: transpose + fp32->bf16 (+ zero-pad K for edge-embed L1).
// Also zeroes deg[] and the fp32 atomic buffer nfx (saves two launches).
__global__ __launch_bounds__(256) void wprep_k(
    const float* __restrict__ mew0, const float* __restrict__ mew1, const float* __restrict__ mnw0,
    const float* __restrict__ eew0, const float* __restrict__ eew1, const float* __restrict__ cw0,
    const float* __restrict__ new0, const float* __restrict__ new1,
    unsigned short* __restrict__ w0T, unsigned short* __restrict__ w1T,
    unsigned short* __restrict__ wmT, unsigned short* __restrict__ w0eT,
    unsigned short* __restrict__ w1eT, unsigned short* __restrict__ cw0T,
    unsigned short* __restrict__ w0nT, unsigned short* __restrict__ w1nT,
    int* __restrict__ deg, float* __restrict__ nfx, int N)
{
    int idx = blockIdx.x * 256 + threadIdx.x;
    if (idx < 49152) {
        int c = idx / 768, k = idx % 768;
        w0T[idx] = f2bf(mew0[k * 64 + c]);
    } else if (idx < 57344) {
        int j = idx - 49152; int c = j / 64, k = j % 64;
        w1T[j] = f2bf(mew1[k * 128 + c]);
    } else if (idx < 106496) {
        int j = idx - 57344; int c = j / 384, k = j % 384;
        wmT[j] = f2bf(mnw0[k * 128 + c]);
    } else if (idx < 126976) {
        int j = idx - 106496; int c = j / KPAD, k = j % KPAD;
        w0eT[j] = (k < EIN) ? f2bf(eew0[k * 64 + c]) : (unsigned short)0;
    } else if (idx < 135168) {
        int j = idx - 126976; int c = j / 64, k = j % 64;
        w1eT[j] = f2bf(eew1[k * 128 + c]);
    } else if (idx < 143360) {
        int j = idx - 135168; int c = j / 128, k = j % 128;
        cw0T[j] = f2bf(cw0[k * 64 + c]);
    } else if (idx < 159744) {
        int j = idx - 143360; int c = j / 128, k = j % 128;
        w0nT[j] = f2bf(new0[k * 128 + c]);
    } else if (idx < 176128) {
        int j = idx - 159744; int c = j / 128, k = j % 128;
        w1nT[j] = f2bf(new1[k * 128 + c]);
    } else if (idx < 176128 + N) {
        deg[idx - 176128] = 0;
    } else if (idx < 176128 + N + (N * ND) / 4) {
        ((float4*)nfx)[idx - 176128 - N] = make_float4(0.f, 0.f, 0.f, 0.f);
    }
}

// FUSED embeds: blocks [0,GSE) run the edge-embed body (co-resident, 3 tiles
// each, CSR-permuted rows); blocks [GSE, GSE+nblocks) run node-embed.
__global__ __launch_bounds__(256, 3) void embed_k(
    // edge part
    const float* __restrict__ ea, const int* __restrict__ csr_eid,
    const unsigned short* __restrict__ w0eT, const float* __restrict__ eb0,
    const unsigned short* __restrict__ w1eT, const float* __restrict__ eb1,
    unsigned short* __restrict__ ef0_bf, unsigned short* __restrict__ ef_bf,
    int E, int ntiles,
    // node part
    const float* __restrict__ x,
    const unsigned short* __restrict__ w0nT, const float* __restrict__ nb0,
    const unsigned short* __restrict__ w1nT, const float* __restrict__ nb1,
    unsigned short* __restrict__ nf0_bf, unsigned short* __restrict__ nf_bf, int N)
{
    __shared__ unsigned short smem[22656];    // 45.3KB union
    const int t = threadIdx.x;
    const int w = t >> 6, lane = t & 63, quad = lane >> 4, n16 = lane & 15;

    if (blockIdx.x < GSE) {
        // ================= edge embed =================
        unsigned short* w0reg = smem;               // 10240 shorts (20KB)
        unsigned short* w1reg = smem + 10240;       // 8192 shorts (16KB)
        unsigned short* hsl   = smem + 18432;       // 4224 shorts ([4][16*66])

        stage_frags<8, 2, 64>(w1eT, w1reg, t, 0);   // covered by first barrier below

        int ng = 0;
        int tile[MAXGE];
#pragma unroll
        for (int g = 0; g < MAXGE; g++) {
            int tl = blockIdx.x + g * GSE;
            if (tl < ntiles) { tile[g] = tl; ng = g + 1; }
            else tile[g] = 0;
        }

        float4_ accL[MAXGE][4];
#pragma unroll
        for (int g = 0; g < MAXGE; g++)
#pragma unroll
            for (int q = 0; q < 4; q++) accL[g][q] = (float4_){0.f, 0.f, 0.f, 0.f};

#pragma unroll
        for (int hf = 0; hf < 2; hf++) {
            __syncthreads();
            stage_frags<4, 5, KPAD>(w0eT, w0reg, t, hf * 160);
            __syncthreads();
#pragma unroll
            for (int g = 0; g < MAXGE; g++) {
                if (g < ng) {
                    int p = tile[g] * 64 + w * 16 + n16; if (p >= E) p = E - 1;
                    const float* src = ea + (size_t)csr_eid[p] * EIN;
#pragma unroll
                    for (int kc = 0; kc < 5; kc++) {
                        int k = hf * 160 + kc * 32 + quad * 8;
                        union { short8 s; uint4 u; } av;
                        if (k + 8 <= EIN) {
                            float4 v0 = *(const float4*)(src + k);
                            float4 v1 = *(const float4*)(src + k + 4);
                            av.u.x = (unsigned)f2bf(v0.x) | ((unsigned)f2bf(v0.y) << 16);
                            av.u.y = (unsigned)f2bf(v0.z) | ((unsigned)f2bf(v0.w) << 16);
                            av.u.z = (unsigned)f2bf(v1.x) | ((unsigned)f2bf(v1.y) << 16);
                            av.u.w = (unsigned)f2bf(v1.z) | ((unsigned)f2bf(v1.w) << 16);
                        } else {
                            unsigned short vv[8];
#pragma unroll
                            for (int j = 0; j < 8; j++)
                                vv[j] = (k + j < EIN) ? f2bf(src[k + j]) : (unsigned short)0;
                            av.u.x = (unsigned)vv[0] | ((unsigned)vv[1] << 16);
                            av.u.y = (unsigned)vv[2] | ((unsigned)vv[3] << 16);
                            av.u.z = (unsigned)vv[4] | ((unsigned)vv[5] << 16);
                            av.u.w = (unsigned)vv[6] | ((unsigned)vv[7] << 16);
                        }
#pragma unroll
                        for (int tt = 0; tt < 4; tt++) {
                            short8 b = FRAG(w0reg, tt * 5 + kc, lane);
                            accL[g][tt] = __builtin_amdgcn_mfma_f32_16x16x32_bf16(av.s, b, accL[g][tt], 0, 0, 0);
                        }
                    }
                }
            }
        }

        // epilogue per tile: bias+ReLU -> per-wave hsl (C->A transform), then L2
#pragma unroll
        for (int g = 0; g < MAXGE; g++) {
            if (g < ng) {
#pragma unroll
                for (int tt = 0; tt < 4; tt++) {
                    int c = tt * 16 + n16;
                    float bias = eb0[c];
#pragma unroll
                    for (int r4 = 0; r4 < 4; r4++)
                        hsl[w * 1056 + (quad * 4 + r4) * 66 + c] = f2bf(fmaxf(accL[g][tt][r4] + bias, 0.f));
                }
                float4_ acc2[8];
#pragma unroll
                for (int q = 0; q < 8; q++) acc2[q] = (float4_){0.f, 0.f, 0.f, 0.f};
#pragma unroll
                for (int kc = 0; kc < 2; kc++) {
                    short8 a2 = *(const short8*)&hsl[w * 1056 + n16 * 66 + kc * 32 + quad * 8];
#pragma unroll
                    for (int tt = 0; tt < 8; tt++)
                        acc2[tt] = __builtin_amdgcn_mfma_f32_16x16x32_bf16(
                            a2, FRAG(w1reg, tt * 2 + kc, lane), acc2[tt], 0, 0, 0);
                }
#pragma unroll
                for (int tt = 0; tt < 8; tt++) {
                    int c = tt * 16 + n16;
                    float bias = eb1[c];
#pragma unroll
                    for (int r4 = 0; r4 < 4; r4++) {
                        int p = tile[g] * 64 + w * 16 + quad * 4 + r4;
                        if (p < E) {
                            unsigned short v = f2bf(acc2[tt][r4] + bias);  // no ReLU
                            ef0_bf[(size_t)p * ED + c] = v;
                            ef_bf[(size_t)p * ED + c] = v;
                        }
                    }
                }
            }
        }
    } else {
        // ================= node embed =================
        unsigned short* wreg = smem;                // 8192 shorts (16KB)
        unsigned short* xin  = smem + 8192;         // [32][130]
        unsigned short* h_bf = smem + 12352;        // [32][130]
        const int n0 = (blockIdx.x - GSE) * TM;

#pragma unroll
        for (int it = 0; it < 4; it++) {
            int idx = it * 256 + t;
            int r = idx >> 5, c4 = idx & 31;
            int node = n0 + r; if (node >= N) node = N - 1;
            float4 v = *(const float4*)(x + (size_t)node * NIN + c4 * 4);
            unsigned lo = (unsigned)f2bf(v.x) | ((unsigned)f2bf(v.y) << 16);
            unsigned hi = (unsigned)f2bf(v.z) | ((unsigned)f2bf(v.w) << 16);
            *(uint2*)&xin[r * 130 + c4 * 4] = make_uint2(lo, hi);
        }

        const int m = w & 1, nh = w >> 1;

        float4_ acc[4];
#pragma unroll
        for (int q = 0; q < 4; q++) acc[q] = (float4_){0.f, 0.f, 0.f, 0.f};
#pragma unroll
        for (int hf = 0; hf < 2; hf++) {
            stage_frags<8, 2, 128>(w0nT, wreg, t, hf * 64);
            __syncthreads();
#pragma unroll
            for (int kc = 0; kc < 2; kc++) {
                short8 a = *(const short8*)&xin[(m * 16 + n16) * 130 + hf * 64 + kc * 32 + quad * 8];
#pragma unroll
                for (int tt = 0; tt < 4; tt++) {
                    short8 b = FRAG(wreg, (nh * 4 + tt) * 2 + kc, lane);
                    acc[tt] = __builtin_amdgcn_mfma_f32_16x16x32_bf16(a, b, acc[tt], 0, 0, 0);
                }
            }
            __syncthreads();
        }
#pragma unroll
        for (int tt = 0; tt < 4; tt++) {
            int c = nh * 64 + tt * 16 + n16;
            float bias = nb0[c];
#pragma unroll
            for (int r4 = 0; r4 < 4; r4++)
                h_bf[(m * 16 + quad * 4 + r4) * 130 + c] = f2bf(fmaxf(acc[tt][r4] + bias, 0.f));
        }
        __syncthreads();

        float4_ acc2[4];
#pragma unroll
        for (int q = 0; q < 4; q++) acc2[q] = (float4_){0.f, 0.f, 0.f, 0.f};
#pragma unroll
        for (int hf = 0; hf < 2; hf++) {
            stage_frags<8, 2, 128>(w1nT, wreg, t, hf * 64);
            __syncthreads();
#pragma unroll
            for (int kc = 0; kc < 2; kc++) {
                short8 a = *(const short8*)&h_bf[(m * 16 + n16) * 130 + hf * 64 + kc * 32 + quad * 8];
#pragma unroll
                for (int tt = 0; tt < 4; tt++) {
                    short8 b = FRAG(wreg, (nh * 4 + tt) * 2 + kc, lane);
                    acc2[tt] = __builtin_amdgcn_mfma_f32_16x16x32_bf16(a, b, acc2[tt], 0, 0, 0);
                }
            }
            __syncthreads();
        }
#pragma unroll
        for (int tt = 0; tt < 4; tt++) {
            int c = nh * 64 + tt * 16 + n16;
            float bias = nb1[c];
#pragma unroll
            for (int r4 = 0; r4 < 4; r4++) {
                int row = m * 16 + quad * 4 + r4;
                int node = n0 + row;
                if (node < N) {
                    unsigned short v = f2bf(acc2[tt][r4] + bias);
                    nf0_bf[(size_t)node * ND + c] = v;
                    nf_bf[(size_t)node * ND + c] = v;
                }
            }
        }
    }
}

// Shared device body for one 64-edge MPN step tile (v6 structure: CSR order,
// fused aggregation, 16KB weight chunks). smem: wreg[8192] + hef[4*2080].
__device__ __forceinline__ void step_tile_body(
    int tile, int E, int wmsg,
    const int* __restrict__ srcp, const int* __restrict__ tgtp,
    const unsigned short* __restrict__ nf0_bf, const unsigned short* __restrict__ nf_in,
    const unsigned short* __restrict__ ef0_bf, unsigned short* __restrict__ ef_bf,
    unsigned short* __restrict__ nf_out, float* __restrict__ nfx,
    const unsigned short* __restrict__ w0T, const float* __restrict__ meb0,
    const unsigned short* __restrict__ w1T, const float* __restrict__ meb1,
    const unsigned short* __restrict__ wmT, const float* __restrict__ mnb0,
    unsigned short* __restrict__ wreg, unsigned short* __restrict__ hef,
    int t, int w, int lane, int quad, int n16)
{
    const int e0 = tile * TS;
    int ec = e0 + w * 16 + n16; if (ec >= E) ec = E - 1;
    const int ti = tgtp[ec], sj = srcp[ec];
    unsigned short* hw = hef + w * 2080;

    const unsigned short* pA[6] = {
        nf0_bf + (size_t)ti * ND + quad * 8,
        nf_in  + (size_t)ti * ND + quad * 8,
        nf0_bf + (size_t)sj * ND + quad * 8,
        nf_in  + (size_t)sj * ND + quad * 8,
        ef0_bf + (size_t)ec * ED + quad * 8,
        ef_bf  + (size_t)ec * ED + quad * 8 };

    // ---- edge MLP layer 0: [64x768]x[768->64], K in 6 chunks of 128 ----
    float4_ accL[4];
#pragma unroll
    for (int q = 0; q < 4; q++) accL[q] = (float4_){0.f, 0.f, 0.f, 0.f};
#pragma unroll
    for (int hf = 0; hf < 6; hf++) {
        short8 a4[4];
#pragma unroll
        for (int q2 = 0; q2 < 4; q2++)
            a4[q2] = *(const short8*)(pA[hf] + q2 * 32);
        stage_frags<4, 4, 768>(w0T, wreg, t, hf * 128);
        __syncthreads();
#pragma unroll
        for (int kc = 0; kc < 4; kc++) {
#pragma unroll
            for (int tt = 0; tt < 4; tt++) {
                short8 b = FRAG(wreg, tt * 4 + kc, lane);
                accL[tt] = __builtin_amdgcn_mfma_f32_16x16x32_bf16(a4[kc], b, accL[tt], 0, 0, 0);
            }
        }
        __syncthreads();
    }

    // L0 epilogue -> h in own-wave band (stride 66)
#pragma unroll
    for (int tt = 0; tt < 4; tt++) {
        int c = tt * 16 + n16;
        float bias = meb0[c];
#pragma unroll
        for (int r4 = 0; r4 < 4; r4++)
            hw[(quad * 4 + r4) * 66 + c] = f2bf(fmaxf(accL[tt][r4] + bias, 0.f));
    }

    // ---- edge MLP layer 1: [64x64]x[64->128] ----
    stage_frags<8, 2, 64>(w1T, wreg, t, 0);
    __syncthreads();
    {
        float4_ acc[8];
#pragma unroll
        for (int q = 0; q < 8; q++) acc[q] = (float4_){0.f, 0.f, 0.f, 0.f};
#pragma unroll
        for (int kc = 0; kc < 2; kc++) {
            short8 a = *(const short8*)&hw[n16 * 66 + kc * 32 + quad * 8];
#pragma unroll
            for (int tt = 0; tt < 8; tt++) {
                short8 b = FRAG(wreg, tt * 2 + kc, lane);
                acc[tt] = __builtin_amdgcn_mfma_f32_16x16x32_bf16(a, b, acc[tt], 0, 0, 0);
            }
        }
#pragma unroll
        for (int tt = 0; tt < 8; tt++) {
            int c = tt * 16 + n16;
            float bias = meb1[c];
#pragma unroll
            for (int r4 = 0; r4 < 4; r4++) {
                int row = quad * 4 + r4;
                unsigned short v = f2bf(fmaxf(acc[tt][r4] + bias, 0.f));
                hw[row * 130 + c] = v;
                int e = e0 + w * 16 + row;
                if (e < E) ef_bf[(size_t)e * ED + c] = v;
            }
        }
    }
    __syncthreads();

    // ---- node-message MLP + fused aggregation ----
    if (wmsg) {
        float4_ accM[8];
#pragma unroll
        for (int q = 0; q < 8; q++) accM[q] = (float4_){0.f, 0.f, 0.f, 0.f};
#pragma unroll
        for (int j = 0; j < 6; j++) {
            short8 a2[2];
#pragma unroll
            for (int kc = 0; kc < 2; kc++) {
                int kk = j * 2 + kc;
                if (kk < 8) a2[kc] = *(const short8*)(pA[kk >> 2] + (kk & 3) * 32);
                else        a2[kc] = *(const short8*)&hw[n16 * 130 + (kk - 8) * 32 + quad * 8];
            }
            stage_frags<8, 2, 384>(wmT, wreg, t, j * 64);
            __syncthreads();
#pragma unroll
            for (int kc = 0; kc < 2; kc++) {
#pragma unroll
                for (int tt = 0; tt < 8; tt++) {
                    short8 b = FRAG(wreg, tt * 2 + kc, lane);
                    accM[tt] = __builtin_amdgcn_mfma_f32_16x16x32_bf16(a2[kc], b, accM[tt], 0, 0, 0);
                }
            }
            __syncthreads();
        }

        // stash msg tile (bias+ReLU, bf16) into wreg as [64][128]
#pragma unroll
        for (int tt = 0; tt < 8; tt++) {
            int c = tt * 16 + n16;
            float bias = mnb0[c];
#pragma unroll
            for (int r4 = 0; r4 < 4; r4++) {
                int row = w * 16 + quad * 4 + r4;
                wreg[row * 128 + c] = f2bf(fmaxf(accM[tt][r4] + bias, 0.f));
            }
        }
        int* tg = (int*)hef;
        if (t < 66) {
            int p = e0 - 1 + t;
            tg[t] = (p >= 0 && p < E) ? tgtp[p] : -1;
        }
        __syncthreads();
        {
            int c = t & 127, half = t >> 7;
            int r0 = half * 32;
            float acc = 0.f;
            int rs = 0;
            for (int r = 0; r < 32; r++) {
                int p = e0 + r0 + r;
                if (p >= E) break;
                int n = tg[r0 + r + 1];
                acc += bf2f(wreg[(r0 + r) * 128 + c]);
                bool end_here = (tg[r0 + r + 2] != n);
                if (end_here) {
                    bool beg_in = (rs > 0) || (tg[r0] != n);
                    if (beg_in) nf_out[(size_t)n * ND + c] = f2bf(acc);
                    else        atomicAdd(&nfx[(size_t)n * ND + c], acc);
                    acc = 0.f; rs = r + 1;
                } else if (r == 31) {
                    atomicAdd(&nfx[(size_t)n * ND + c], acc);
                }
            }
        }
    }
}

// COOPERATIVE fused MPN: 4 steps + 3 fixups + classify in ONE dispatch.
// Grid = 1024 (4/CU x 256 CU, LDS 33KB, VGPR<=128). Replaces 8 dependent
// dispatches (~9us boundary each) with grid.sync (~3-5us each).
__global__ __launch_bounds__(256, 4) void mpn_fused_k(
    const int* __restrict__ srcp, const int* __restrict__ tgtp,
    const int* __restrict__ row_ptr, const int* __restrict__ csr_eid,
    const unsigned short* __restrict__ nf0_bf,
    unsigned short* __restrict__ nfA, unsigned short* __restrict__ nfB,
    const unsigned short* __restrict__ ef0_bf, unsigned short* __restrict__ ef_bf,
    float* __restrict__ nfx,
    const unsigned short* __restrict__ w0T, const float* __restrict__ meb0,
    const unsigned short* __restrict__ w1T, const float* __restrict__ meb1,
    const unsigned short* __restrict__ wmT, const float* __restrict__ mnb0,
    const unsigned short* __restrict__ cw0T, const float* __restrict__ cb0,
    const float* __restrict__ cw1, const float* __restrict__ cb1,
    const float* __restrict__ cw2, const float* __restrict__ cb2,
    float* __restrict__ out,
    int E, int N, int ntiles)
{
    cg::grid_group grid = cg::this_grid();
    __shared__ unsigned short smem[16512];   // 33KB: wreg[8192] + hef[4*2080]
    unsigned short* wreg = smem;
    unsigned short* hef  = smem + 8192;

    const int t = threadIdx.x;
    const int w = t >> 6, lane = t & 63, quad = lane >> 4, n16 = lane & 15;

    const unsigned short* nfR = nfA;
    unsigned short* nfW = nfB;

    for (int s = 0; s < 4; s++) {
        const int wmsg = (s < 3) ? 1 : 0;
        for (int tile = blockIdx.x; tile < ntiles; tile += (int)gridDim.x) {
            step_tile_body(tile, E, wmsg, srcp, tgtp, nf0_bf, nfR,
                           ef0_bf, ef_bf, nfW, nfx,
                           w0T, meb0, w1T, meb1, wmT, mnb0,
                           wreg, hef, t, w, lane, quad, n16);
            __syncthreads();   // protect smem reuse across tile iterations
        }
        __threadfence();
        grid.sync();
        if (wmsg) {
            // fixup, grid-stride (2 nodes per block-iteration)
            for (int base = blockIdx.x * 2; base < N; base += (int)gridDim.x * 2) {
                int n = base + (t >> 7);
                int c = t & 127;
                if (n < N) {
                    int beg = row_ptr[n], end = row_ptr[n + 1];
                    if (beg == end) nfW[(size_t)n * ND + c] = 0;
                    else if ((beg >> 5) != ((end - 1) >> 5)) {
                        size_t idx = (size_t)n * ND + c;
                        nfW[idx] = f2bf(nfx[idx]);
                        nfx[idx] = 0.f;
                    }
                }
            }
            __threadfence();
            grid.sync();
            unsigned short* tmp = (unsigned short*)nfR; nfR = nfW; nfW = tmp;
        }
    }

    // ---- classify, grid-stride over 32-edge tiles ----
    unsigned short* h0_bf = smem;              // [TM][66]
    float* h1 = (float*)(smem + 2112);         // [TM][33]
    const int eblocks = (E + TM - 1) / TM;
    const int m = w & 1;
    for (int eb = blockIdx.x; eb < eblocks; eb += (int)gridDim.x) {
        const int e0c = eb * TM;
        int ec = e0c + m * 16 + n16; if (ec >= E) ec = E - 1;
        const unsigned short* pa = ef_bf + (size_t)ec * ED + quad * 8;
        {
            const int cb = (w >> 1) * 32;
            float4_ acc0 = {0.f, 0.f, 0.f, 0.f}, acc1 = acc0;
            const unsigned short* b0p = cw0T + (size_t)(cb + n16) * 128 + quad * 8;
            const unsigned short* b1p = b0p + (size_t)16 * 128;
#pragma unroll
            for (int kc = 0; kc < 4; kc++) {
                short8 a  = *(const short8*)(pa + kc * 32);
                short8 bb0 = *(const short8*)(b0p + kc * 32);
                short8 bb1 = *(const short8*)(b1p + kc * 32);
                acc0 = __builtin_amdgcn_mfma_f32_16x16x32_bf16(a, bb0, acc0, 0, 0, 0);
                acc1 = __builtin_amdgcn_mfma_f32_16x16x32_bf16(a, bb1, acc1, 0, 0, 0);
            }
#pragma unroll
            for (int t2 = 0; t2 < 2; t2++) {
                int c = cb + t2 * 16 + n16;
                float bias = cb0[c];
                float4_ ac = t2 ? acc1 : acc0;
#pragma unroll
                for (int r4 = 0; r4 < 4; r4++)
                    h0_bf[(m * 16 + quad * 4 + r4) * 66 + c] = f2bf(fmaxf(ac[r4] + bias, 0.f));
            }
        }
        __syncthreads();
        {
            int c = t & 31;
            int rbase = (t >> 5) * 4;
#pragma unroll
            for (int q = 0; q < 4; q++) {
                int r = rbase + q;
                float acc = cb1[c];
#pragma unroll 8
                for (int k = 0; k < 64; k++) acc += bf2f(h0_bf[r * 66 + k]) * cw1[k * 32 + c];
                h1[r * 33 + c] = fmaxf(acc, 0.f);
            }
        }
        __syncthreads();
        if (t < TM) {
            int p = e0c + t;
            if (p < E) {
                float a = cb2[0];
#pragma unroll
                for (int k = 0; k < 32; k++) a += h1[t * 33 + k] * cw2[k];
                out[csr_eid[p]] = a;
            }
        }
        __syncthreads();
    }
}

// Fallback standalone kernels (used if cooperative launch is unavailable).
__global__ __launch_bounds__(256, 4) void edge_step_k(
    const int* __restrict__ srcp, const int* __restrict__ tgtp,
    const unsigned short* __restrict__ nf0_bf, const unsigned short* __restrict__ nf_in,
    const unsigned short* __restrict__ ef0_bf, unsigned short* __restrict__ ef_bf,
    unsigned short* __restrict__ nf_out, float* __restrict__ nfx,
    const unsigned short* __restrict__ w0T, const float* __restrict__ meb0,
    const unsigned short* __restrict__ w1T, const float* __restrict__ meb1,
    const unsigned short* __restrict__ wmT, const float* __restrict__ mnb0,
    int E, int wmsg)
{
    __shared__ unsigned short smem[16512];
    const int t = threadIdx.x;
    const int w = t >> 6, lane = t & 63, quad = lane >> 4, n16 = lane & 15;
    step_tile_body(blockIdx.x, E, wmsg, srcp, tgtp, nf0_bf, nf_in,
                   ef0_bf, ef_bf, nf_out, nfx,
                   w0T, meb0, w1T, meb1, wmT, mnb0,
                   smem, smem + 8192, t, w, lane, quad, n16);
}

__global__ __launch_bounds__(256) void classify_k(
    const unsigned short* __restrict__ ef_bf, const int* __restrict__ csr_eid,
    const unsigned short* __restrict__ cw0T, const float* __restrict__ cb0,
    const float* __restrict__ cw1, const float* __restrict__ cb1,
    const float* __restrict__ cw2, const float* __restrict__ cb2,
    float* __restrict__ out, int E)
{
    const int t = threadIdx.x;
    const int e0 = blockIdx.x * TM;
    __shared__ unsigned short h0_bf[TM][66];
    __shared__ float h1[TM][33];

    const int w = t >> 6, lane = t & 63, quad = lane >> 4, n16 = lane & 15;
    const int m = w & 1;
    int ec = e0 + m * 16 + n16; if (ec >= E) ec = E - 1;
    const unsigned short* pa = ef_bf + (size_t)ec * ED + quad * 8;

    {
        const int cb = (w >> 1) * 32;
        float4_ acc0 = {0.f, 0.f, 0.f, 0.f}, acc1 = acc0;
        const unsigned short* b0p = cw0T + (size_t)(cb + n16) * 128 + quad * 8;
        const unsigned short* b1p = b0p + (size_t)16 * 128;
#pragma unroll
        for (int kc = 0; kc < 4; kc++) {
            short8 a  = *(const short8*)(pa + kc * 32);
            short8 bb0 = *(const short8*)(b0p + kc * 32);
            short8 bb1 = *(const short8*)(b1p + kc * 32);
            acc0 = __builtin_amdgcn_mfma_f32_16x16x32_bf16(a, bb0, acc0, 0, 0, 0);
            acc1 = __builtin_amdgcn_mfma_f32_16x16x32_bf16(a, bb1, acc1, 0, 0, 0);
        }
#pragma unroll
        for (int t2 = 0; t2 < 2; t2++) {
            int c = cb + t2 * 16 + n16;
            float bias = cb0[c];
            float4_ ac = t2 ? acc1 : acc0;
#pragma unroll
            for (int r4 = 0; r4 < 4; r4++)
                h0_bf[m * 16 + quad * 4 + r4][c] = f2bf(fmaxf(ac[r4] + bias, 0.f));
        }
    }
    __syncthreads();

    {
        int c = t & 31;
        int rbase = (t >> 5) * 4;
#pragma unroll
        for (int q = 0; q < 4; q++) {
            int r = rbase + q;
            float acc = cb1[c];
#pragma unroll 8
            for (int k = 0; k < 64; k++) acc += bf2f(h0_bf[r][k]) * cw1[k * 32 + c];
            h1[r][c] = fmaxf(acc, 0.f);
        }
    }
    __syncthreads();

    if (t < TM) {
        int p = e0 + t;
        if (p < E) {
            float a = cb2[0];
#pragma unroll
            for (int k = 0; k < 32; k++) a += h1[t][k] * cw2[k];
            out[csr_eid[p]] = a;
        }
    }
}

extern "C" void kernel_launch(void* const* d_in, const int* in_sizes, int n_in,
                              void* d_out, int out_size, void* d_ws, size_t ws_size,
                              hipStream_t stream)
{
    const float* x    = (const float*)d_in[0];
    const float* ea   = (const float*)d_in[1];
    const int*   eidx = (const int*)d_in[2];
    const float* new0 = (const float*)d_in[3];  const float* neb0 = (const float*)d_in[4];
    const float* new1 = (const float*)d_in[5];  const float* neb1 = (const float*)d_in[6];
    const float* eew0 = (const float*)d_in[7];  const float* eeb0 = (const float*)d_in[8];
    const float* eew1 = (const float*)d_in[9];  const float* eeb1 = (const float*)d_in[10];
    const float* mew0 = (const float*)d_in[11]; const float* meb0 = (const float*)d_in[12];
    const float* mew1 = (const float*)d_in[13]; const float* meb1 = (const float*)d_in[14];
    const float* mnw0 = (const float*)d_in[15]; const float* mnb0 = (const float*)d_in[16];
    const float* cw0  = (const float*)d_in[17]; const float* cb0  = (const float*)d_in[18];
    const float* cw1  = (const float*)d_in[19]; const float* cb1  = (const float*)d_in[20];
    const float* cw2  = (const float*)d_in[21]; const float* cb2  = (const float*)d_in[22];

    const int N = in_sizes[0] / NIN;   // 20000
    const int E = in_sizes[2] / 2;     // 100000
    const int* srcj = eidx;            // edge_index[0] = j (source)
    const int* tgti = eidx + E;        // edge_index[1] = i (target)

    char* wsb = (char*)d_ws;
    unsigned short* nf0_bf = (unsigned short*)wsb;          // N*ND
    unsigned short* nfA    = nf0_bf + (size_t)N * ND;       // N*ND (read buf)
    unsigned short* ef0_bf = nfA + (size_t)N * ND;
    unsigned short* ef_bf  = ef0_bf + (size_t)E * ED;
    unsigned short* slot   = ef_bf + (size_t)E * ED;
    unsigned short* nfB    = slot;                          // N*ND bf16 (write buf)
    float*          nfx    = (float*)(slot + (size_t)N * ND); // N*ND fp32 atomics
    unsigned short* w0T  = slot + (size_t)E * ND;           // [64][768]
    unsigned short* w1T  = w0T + 49152;                     // [128][64]
    unsigned short* wmT  = w1T + 8192;                      // [128][384]
    unsigned short* w0eT = wmT + 49152;                     // [64][KPAD]
    unsigned short* w1eT = w0eT + 64 * KPAD;                // [128][64]
    unsigned short* cw0T = w1eT + 8192;                     // [64][128]
    unsigned short* w0nT = cw0T + 8192;                     // [128][128]
    unsigned short* w1nT = w0nT + 16384;                    // [128][128]
    int* deg     = (int*)(w1nT + 16384);                    // N
    int* cursor  = deg + N;                                 // N (contiguous w/ deg)
    int* row_ptr = cursor + N;                              // N+1
    int* csr_eid = row_ptr + (N + 4);                       // E
    int* srcp    = csr_eid + E;                             // E (CSR-order source)
    int* tgtp    = srcp + E;                                // E (CSR-order target, sorted)

    const int eblocks32 = (E + TM - 1) / TM;
    const int nblocks32 = (N + TM - 1) / TM;
    const int ntiles64 = (E + 63) / 64;

    const int wprep_items = 176128 + N + (N * ND) / 4;
    wprep_k<<<(wprep_items + 255) / 256, 256, 0, stream>>>(mew0, mew1, mnw0, eew0, eew1, cw0,
                                                           new0, new1,
                                                           w0T, w1T, wmT, w0eT, w1eT, cw0T,
                                                           w0nT, w1nT, deg, nfx, N);

    // CSR build (edge_index is constant across all 4 steps)
    hist_k<<<(E + 255) / 256, 256, 0, stream>>>(tgti, deg, E);
    scan_k<<<1, 256, 0, stream>>>(deg, row_ptr, cursor, N, E);
    scatter_k<<<(E + 255) / 256, 256, 0, stream>>>(srcj, tgti, cursor, csr_eid, srcp, tgtp, E);

    // fused node+edge embed
    embed_k<<<GSE + nblocks32, 256, 0, stream>>>(ea, csr_eid, w0eT, eeb0, w1eT, eeb1,
                                                 ef0_bf, ef_bf, E, ntiles64,
                                                 x, w0nT, neb0, w1nT, neb1,
                                                 nf0_bf, nfA, N);

    // cooperative fused MPN (4 steps + fixups + classify in one dispatch)
    {
        float* outp = (float*)d_out;
        int E_ = E, N_ = N, nt_ = ntiles64;
        void* kargs[] = {
            (void*)&srcp, (void*)&tgtp, (void*)&row_ptr, (void*)&csr_eid,
            (void*)&nf0_bf, (void*)&nfA, (void*)&nfB, (void*)&ef0_bf, (void*)&ef_bf,
            (void*)&nfx, (void*)&w0T, (void*)&meb0, (void*)&w1T, (void*)&meb1,
            (void*)&wmT, (void*)&mnb0, (void*)&cw0T, (void*)&cb0, (void*)&cw1,
            (void*)&cb1, (void*)&cw2, (void*)&cb2, (void*)&outp,
            (void*)&E_, (void*)&N_, (void*)&nt_ };
        hipError_t err = hipLaunchCooperativeKernel((void*)mpn_fused_k,
                                                    dim3(CGRID), dim3(256),
                                                    kargs, 0, stream);
        if (err != hipSuccess) {
            // Fallback: proven multi-launch path.
            unsigned short* nfR = nfA;
            unsigned short* nfW = nfB;
            for (int s = 0; s < 4; s++) {
                edge_step_k<<<ntiles64, 256, 0, stream>>>(srcp, tgtp, nf0_bf, nfR,
                                                          ef0_bf, ef_bf, nfW, nfx,
                                                          w0T, meb0, w1T, meb1, wmT, mnb0,
                                                          E, (s < 3) ? 1 : 0);
                if (s < 3) {
                    fixup_k<<<(N + 1) / 2, 256, 0, stream>>>(row_ptr, nfx, nfW, N);
                    unsigned short* tmp = nfR; nfR = nfW; nfW = tmp;
                }
            }
            classify_k<<<eblocks32, 256, 0, stream>>>(ef_bf, csr_eid, cw0T, cb0,
                                                      cw1, cb1, cw2, cb2,
                                                      (float*)d_out, E);
        }
    }
}

// Round 17
// 637.753 us; speedup vs baseline: 3.4785x; 3.4785x over previous
//
#include <hip/hip_runtime.h>
#include <hip/hip_bf16.h>

#define ND 128
#define ED 128
#define NIN 128
#define EIN 291
#define KPAD 320   // EIN padded to multiple of 32 (w0eT row stride)
#define HH 64
#define TM 32
#define TS 64      // edges per block in edge_step
#define GSE 768    // grid blocks for edge_embed part (3 per CU)
#define MAXGE 3    // max 64-edge tiles per edge_embed block

typedef __attribute__((ext_vector_type(8))) short short8;
typedef __attribute__((ext_vector_type(4))) float float4_;

__device__ __forceinline__ unsigned short f2bf(float f)
{
    union { float f; unsigned u; } v; v.f = f;
    unsigned u = v.u;
    unsigned r = (u + 0x7FFFu + ((u >> 16) & 1u)) >> 16;  // RNE
    return (unsigned short)r;
}
__device__ __forceinline__ float bf2f(unsigned short s)
{
    union { unsigned u; float f; } v; v.u = ((unsigned)s) << 16;
    return v.f;
}

// Stage T N-tiles x KC k-chunks of B (layout [col][K], bf16) into LDS in MFMA
// FRAGMENT ORDER: fragment f=tt*KC+kc occupies 64 consecutive short8 slots.
template<int T, int KC, int K>
__device__ __forceinline__ void stage_frags(const unsigned short* __restrict__ src,
                                            unsigned short* __restrict__ wreg,
                                            int t, int k0)
{
    constexpr int TOT = T * KC * 64;
#pragma unroll
    for (int it = 0; it < TOT / 256; it++) {
        int idx = it * 256 + t;
        int f = idx >> 6, l = idx & 63;
        int col = (f / KC) * 16 + (l & 15);
        int k = (f % KC) * 32 + ((l >> 4) * 8);
        *(short8*)&wreg[idx * 8] = *(const short8*)&src[(size_t)col * K + k0 + k];
    }
}
#define FRAG(wreg, f, lane) (*(const short8*)&(wreg)[(((f) << 6) + (lane)) * 8])

// ---- CSR build (once per launch; edge_index is constant across the 4 steps) ----
__global__ __launch_bounds__(256) void hist_k(const int* __restrict__ tgti,
                                              int* __restrict__ deg, int E)
{
    int e = blockIdx.x * 256 + threadIdx.x;
    if (e < E) atomicAdd(&deg[tgti[e]], 1);
}

// Single-block exclusive scan over deg[0..N) -> row_ptr & cursor.
__global__ __launch_bounds__(256) void scan_k(const int* __restrict__ deg,
                                              int* __restrict__ row_ptr,
                                              int* __restrict__ cursor, int N, int E)
{
    __shared__ int part[256];
    const int t = threadIdx.x;
    const int chunk = (N + 255) / 256;
    const int base = t * chunk;
    int s = 0;
    for (int k = 0; k < chunk; k++) { int idx = base + k; if (idx < N) s += deg[idx]; }
    part[t] = s;
    __syncthreads();
    for (int off = 1; off < 256; off <<= 1) {
        int v = (t >= off) ? part[t - off] : 0;
        __syncthreads();
        part[t] += v;
        __syncthreads();
    }
    int run = (t == 0) ? 0 : part[t - 1];
    for (int k = 0; k < chunk; k++) {
        int idx = base + k;
        if (idx < N) { row_ptr[idx] = run; cursor[idx] = run; run += deg[idx]; }
    }
    if (t == 255) row_ptr[N] = E;
}

// scatter + positional perm fused: writes csr_eid, srcp, tgtp in one pass.
__global__ __launch_bounds__(256) void scatter_k(const int* __restrict__ srcj,
                                                 const int* __restrict__ tgti,
                                                 int* __restrict__ cursor,
                                                 int* __restrict__ csr_eid,
                                                 int* __restrict__ srcp,
                                                 int* __restrict__ tgtp, int E)
{
    int e = blockIdx.x * 256 + threadIdx.x;
    if (e < E) {
        int tg = tgti[e];
        int p = atomicAdd(&cursor[tg], 1);
        csr_eid[p] = e;
        srcp[p] = srcj[e];
        tgtp[p] = tg;
    }
}

// Boundary fixup after fused-aggregation edge_step.
__global__ __launch_bounds__(256) void fixup_k(const int* __restrict__ row_ptr,
                                               float* __restrict__ nfx,
                                               unsigned short* __restrict__ nf_out, int N)
{
    int n = blockIdx.x * 2 + (threadIdx.x >> 7);
    int c = threadIdx.x & 127;
    if (n >= N) return;
    int beg = row_ptr[n], end = row_ptr[n + 1];
    if (beg == end) { nf_out[(size_t)n * ND + c] = 0; return; }
    if ((beg >> 5) != ((end - 1) >> 5)) {
        size_t idx = (size_t)n * ND + c;
        nf_out[idx] = f2bf(nfx[idx]);
        nfx[idx] = 0.f;
    }
}

// One-time weight prep: transpose + fp32->bf16 (+ zero-pad K for edge-embed L1).
// Also zeroes deg[] and the fp32 atomic buffer nfx.
__global__ __launch_bounds__(256) void wprep_k(
    const float* __restrict__ mew0, const float* __restrict__ mew1, const float* __restrict__ mnw0,
    const float* __restrict__ eew0, const float* __restrict__ eew1, const float* __restrict__ cw0,
    const float* __restrict__ new0, const float* __restrict__ new1,
    unsigned short* __restrict__ w0T, unsigned short* __restrict__ w1T,
    unsigned short* __restrict__ wmT, unsigned short* __restrict__ w0eT,
    unsigned short* __restrict__ w1eT, unsigned short* __restrict__ cw0T,
    unsigned short* __restrict__ w0nT, unsigned short* __restrict__ w1nT,
    int* __restrict__ deg, float* __restrict__ nfx, int N)
{
    int idx = blockIdx.x * 256 + threadIdx.x;
    if (idx < 49152) {
        int c = idx / 768, k = idx % 768;
        w0T[idx] = f2bf(mew0[k * 64 + c]);
    } else if (idx < 57344) {
        int j = idx - 49152; int c = j / 64, k = j % 64;
        w1T[j] = f2bf(mew1[k * 128 + c]);
    } else if (idx < 106496) {
        int j = idx - 57344; int c = j / 384, k = j % 384;
        wmT[j] = f2bf(mnw0[k * 128 + c]);
    } else if (idx < 126976) {
        int j = idx - 106496; int c = j / KPAD, k = j % KPAD;
        w0eT[j] = (k < EIN) ? f2bf(eew0[k * 64 + c]) : (unsigned short)0;
    } else if (idx < 135168) {
        int j = idx - 126976; int c = j / 64, k = j % 64;
        w1eT[j] = f2bf(eew1[k * 128 + c]);
    } else if (idx < 143360) {
        int j = idx - 135168; int c = j / 128, k = j % 128;
        cw0T[j] = f2bf(cw0[k * 64 + c]);
    } else if (idx < 159744) {
        int j = idx - 143360; int c = j / 128, k = j % 128;
        w0nT[j] = f2bf(new0[k * 128 + c]);
    } else if (idx < 176128) {
        int j = idx - 159744; int c = j / 128, k = j % 128;
        w1nT[j] = f2bf(new1[k * 128 + c]);
    } else if (idx < 176128 + N) {
        deg[idx - 176128] = 0;
    } else if (idx < 176128 + N + (N * ND) / 4) {
        ((float4*)nfx)[idx - 176128 - N] = make_float4(0.f, 0.f, 0.f, 0.f);
    }
}

// FUSED embeds: blocks [0,GSE) edge-embed (co-resident, 3 tiles each,
// CSR-permuted rows); blocks [GSE, GSE+nblocks) node-embed.
__global__ __launch_bounds__(256, 3) void embed_k(
    const float* __restrict__ ea, const int* __restrict__ csr_eid,
    const unsigned short* __restrict__ w0eT, const float* __restrict__ eb0,
    const unsigned short* __restrict__ w1eT, const float* __restrict__ eb1,
    unsigned short* __restrict__ ef0_bf, unsigned short* __restrict__ ef_bf,
    int E, int ntiles,
    const float* __restrict__ x,
    const unsigned short* __restrict__ w0nT, const float* __restrict__ nb0,
    const unsigned short* __restrict__ w1nT, const float* __restrict__ nb1,
    unsigned short* __restrict__ nf0_bf, unsigned short* __restrict__ nf_bf, int N)
{
    __shared__ unsigned short smem[22656];    // 45.3KB union
    const int t = threadIdx.x;
    const int w = t >> 6, lane = t & 63, quad = lane >> 4, n16 = lane & 15;

    if (blockIdx.x < GSE) {
        // ================= edge embed =================
        unsigned short* w0reg = smem;               // 10240 shorts (20KB)
        unsigned short* w1reg = smem + 10240;       // 8192 shorts (16KB)
        unsigned short* hsl   = smem + 18432;       // 4224 shorts ([4][16*66])

        stage_frags<8, 2, 64>(w1eT, w1reg, t, 0);   // covered by first barrier below

        int ng = 0;
        int tile[MAXGE];
#pragma unroll
        for (int g = 0; g < MAXGE; g++) {
            int tl = blockIdx.x + g * GSE;
            if (tl < ntiles) { tile[g] = tl; ng = g + 1; }
            else tile[g] = 0;
        }

        float4_ accL[MAXGE][4];
#pragma unroll
        for (int g = 0; g < MAXGE; g++)
#pragma unroll
            for (int q = 0; q < 4; q++) accL[g][q] = (float4_){0.f, 0.f, 0.f, 0.f};

#pragma unroll
        for (int hf = 0; hf < 2; hf++) {
            __syncthreads();
            stage_frags<4, 5, KPAD>(w0eT, w0reg, t, hf * 160);
            __syncthreads();
#pragma unroll
            for (int g = 0; g < MAXGE; g++) {
                if (g < ng) {
                    int p = tile[g] * 64 + w * 16 + n16; if (p >= E) p = E - 1;
                    const float* src = ea + (size_t)csr_eid[p] * EIN;
#pragma unroll
                    for (int kc = 0; kc < 5; kc++) {
                        int k = hf * 160 + kc * 32 + quad * 8;
                        union { short8 s; uint4 u; } av;
                        if (k + 8 <= EIN) {
                            float4 v0 = *(const float4*)(src + k);
                            float4 v1 = *(const float4*)(src + k + 4);
                            av.u.x = (unsigned)f2bf(v0.x) | ((unsigned)f2bf(v0.y) << 16);
                            av.u.y = (unsigned)f2bf(v0.z) | ((unsigned)f2bf(v0.w) << 16);
                            av.u.z = (unsigned)f2bf(v1.x) | ((unsigned)f2bf(v1.y) << 16);
                            av.u.w = (unsigned)f2bf(v1.z) | ((unsigned)f2bf(v1.w) << 16);
                        } else {
                            unsigned short vv[8];
#pragma unroll
                            for (int j = 0; j < 8; j++)
                                vv[j] = (k + j < EIN) ? f2bf(src[k + j]) : (unsigned short)0;
                            av.u.x = (unsigned)vv[0] | ((unsigned)vv[1] << 16);
                            av.u.y = (unsigned)vv[2] | ((unsigned)vv[3] << 16);
                            av.u.z = (unsigned)vv[4] | ((unsigned)vv[5] << 16);
                            av.u.w = (unsigned)vv[6] | ((unsigned)vv[7] << 16);
                        }
#pragma unroll
                        for (int tt = 0; tt < 4; tt++) {
                            short8 b = FRAG(w0reg, tt * 5 + kc, lane);
                            accL[g][tt] = __builtin_amdgcn_mfma_f32_16x16x32_bf16(av.s, b, accL[g][tt], 0, 0, 0);
                        }
                    }
                }
            }
        }

        // epilogue per tile
#pragma unroll
        for (int g = 0; g < MAXGE; g++) {
            if (g < ng) {
#pragma unroll
                for (int tt = 0; tt < 4; tt++) {
                    int c = tt * 16 + n16;
                    float bias = eb0[c];
#pragma unroll
                    for (int r4 = 0; r4 < 4; r4++)
                        hsl[w * 1056 + (quad * 4 + r4) * 66 + c] = f2bf(fmaxf(accL[g][tt][r4] + bias, 0.f));
                }
                float4_ acc2[8];
#pragma unroll
                for (int q = 0; q < 8; q++) acc2[q] = (float4_){0.f, 0.f, 0.f, 0.f};
#pragma unroll
                for (int kc = 0; kc < 2; kc++) {
                    short8 a2 = *(const short8*)&hsl[w * 1056 + n16 * 66 + kc * 32 + quad * 8];
#pragma unroll
                    for (int tt = 0; tt < 8; tt++)
                        acc2[tt] = __builtin_amdgcn_mfma_f32_16x16x32_bf16(
                            a2, FRAG(w1reg, tt * 2 + kc, lane), acc2[tt], 0, 0, 0);
                }
#pragma unroll
                for (int tt = 0; tt < 8; tt++) {
                    int c = tt * 16 + n16;
                    float bias = eb1[c];
#pragma unroll
                    for (int r4 = 0; r4 < 4; r4++) {
                        int p = tile[g] * 64 + w * 16 + quad * 4 + r4;
                        if (p < E) {
                            unsigned short v = f2bf(acc2[tt][r4] + bias);  // no ReLU
                            ef0_bf[(size_t)p * ED + c] = v;
                            ef_bf[(size_t)p * ED + c] = v;
                        }
                    }
                }
            }
        }
    } else {
        // ================= node embed =================
        unsigned short* wreg = smem;                // 8192 shorts (16KB)
        unsigned short* xin  = smem + 8192;         // [32][130]
        unsigned short* h_bf = smem + 12352;        // [32][130]
        const int n0 = (blockIdx.x - GSE) * TM;

#pragma unroll
        for (int it = 0; it < 4; it++) {
            int idx = it * 256 + t;
            int r = idx >> 5, c4 = idx & 31;
            int node = n0 + r; if (node >= N) node = N - 1;
            float4 v = *(const float4*)(x + (size_t)node * NIN + c4 * 4);
            unsigned lo = (unsigned)f2bf(v.x) | ((unsigned)f2bf(v.y) << 16);
            unsigned hi = (unsigned)f2bf(v.z) | ((unsigned)f2bf(v.w) << 16);
            *(uint2*)&xin[r * 130 + c4 * 4] = make_uint2(lo, hi);
        }

        const int m = w & 1, nh = w >> 1;

        float4_ acc[4];
#pragma unroll
        for (int q = 0; q < 4; q++) acc[q] = (float4_){0.f, 0.f, 0.f, 0.f};
#pragma unroll
        for (int hf = 0; hf < 2; hf++) {
            stage_frags<8, 2, 128>(w0nT, wreg, t, hf * 64);
            __syncthreads();
#pragma unroll
            for (int kc = 0; kc < 2; kc++) {
                short8 a = *(const short8*)&xin[(m * 16 + n16) * 130 + hf * 64 + kc * 32 + quad * 8];
#pragma unroll
                for (int tt = 0; tt < 4; tt++) {
                    short8 b = FRAG(wreg, (nh * 4 + tt) * 2 + kc, lane);
                    acc[tt] = __builtin_amdgcn_mfma_f32_16x16x32_bf16(a, b, acc[tt], 0, 0, 0);
                }
            }
            __syncthreads();
        }
#pragma unroll
        for (int tt = 0; tt < 4; tt++) {
            int c = nh * 64 + tt * 16 + n16;
            float bias = nb0[c];
#pragma unroll
            for (int r4 = 0; r4 < 4; r4++)
                h_bf[(m * 16 + quad * 4 + r4) * 130 + c] = f2bf(fmaxf(acc[tt][r4] + bias, 0.f));
        }
        __syncthreads();

        float4_ acc2[4];
#pragma unroll
        for (int q = 0; q < 4; q++) acc2[q] = (float4_){0.f, 0.f, 0.f, 0.f};
#pragma unroll
        for (int hf = 0; hf < 2; hf++) {
            stage_frags<8, 2, 128>(w1nT, wreg, t, hf * 64);
            __syncthreads();
#pragma unroll
            for (int kc = 0; kc < 2; kc++) {
                short8 a = *(const short8*)&h_bf[(m * 16 + n16) * 130 + hf * 64 + kc * 32 + quad * 8];
#pragma unroll
                for (int tt = 0; tt < 4; tt++) {
                    short8 b = FRAG(wreg, (nh * 4 + tt) * 2 + kc, lane);
                    acc2[tt] = __builtin_amdgcn_mfma_f32_16x16x32_bf16(a, b, acc2[tt], 0, 0, 0);
                }
            }
            __syncthreads();
        }
#pragma unroll
        for (int tt = 0; tt < 4; tt++) {
            int c = nh * 64 + tt * 16 + n16;
            float bias = nb1[c];
#pragma unroll
            for (int r4 = 0; r4 < 4; r4++) {
                int row = m * 16 + quad * 4 + r4;
                int node = n0 + row;
                if (node < N) {
                    unsigned short v = f2bf(acc2[tt][r4] + bias);
                    nf0_bf[(size_t)node * ND + c] = v;
                    nf_bf[(size_t)node * ND + c] = v;
                }
            }
        }
    }
}

// MFMA MPN step v7: CSR order + fused aggregation, 16KB chunks, 4 blocks/CU.
// On the LAST step (wmsg=0), the classify head (ef -> 64 -> 32 -> 1) is fused
// into the epilogue: each wave classifies its 16 edges entirely intra-wave
// using the efn band already in LDS (no separate classify dispatch).
__global__ __launch_bounds__(256, 4) void edge_step_k(
    const int* __restrict__ srcp, const int* __restrict__ tgtp,
    const unsigned short* __restrict__ nf0_bf, const unsigned short* __restrict__ nf_in,
    const unsigned short* __restrict__ ef0_bf, unsigned short* __restrict__ ef_bf,
    unsigned short* __restrict__ nf_out, float* __restrict__ nfx,
    const unsigned short* __restrict__ w0T, const float* __restrict__ meb0,
    const unsigned short* __restrict__ w1T, const float* __restrict__ meb1,
    const unsigned short* __restrict__ wmT, const float* __restrict__ mnb0,
    const int* __restrict__ csr_eid,
    const unsigned short* __restrict__ cw0T, const float* __restrict__ cb0,
    const float* __restrict__ cw1, const float* __restrict__ cb1,
    const float* __restrict__ cw2, const float* __restrict__ cb2,
    float* __restrict__ out,
    int E, int wmsg)
{
    const int t = threadIdx.x;
    const int e0 = blockIdx.x * TS;
    __shared__ unsigned short wreg[8192];      // 16KB weight staging / msg tile [64][128]
    __shared__ unsigned short hef[4][2080];    // per-wave band: h(66) then efn(130)

    const int w = t >> 6, lane = t & 63, quad = lane >> 4, n16 = lane & 15;
    int ec = e0 + w * 16 + n16; if (ec >= E) ec = E - 1;
    const int ti = tgtp[ec], sj = srcp[ec];
    unsigned short* hw = hef[w];

    const unsigned short* pA[6] = {
        nf0_bf + (size_t)ti * ND + quad * 8,
        nf_in  + (size_t)ti * ND + quad * 8,
        nf0_bf + (size_t)sj * ND + quad * 8,
        nf_in  + (size_t)sj * ND + quad * 8,
        ef0_bf + (size_t)ec * ED + quad * 8,
        ef_bf  + (size_t)ec * ED + quad * 8 };

    // ---- edge MLP layer 0: [64x768]x[768->64], K in 6 chunks of 128 ----
    float4_ accL[4];
#pragma unroll
    for (int q = 0; q < 4; q++) accL[q] = (float4_){0.f, 0.f, 0.f, 0.f};
#pragma unroll
    for (int hf = 0; hf < 6; hf++) {
        short8 a4[4];
#pragma unroll
        for (int q2 = 0; q2 < 4; q2++)
            a4[q2] = *(const short8*)(pA[hf] + q2 * 32);
        stage_frags<4, 4, 768>(w0T, wreg, t, hf * 128);
        __syncthreads();
#pragma unroll
        for (int kc = 0; kc < 4; kc++) {
#pragma unroll
            for (int tt = 0; tt < 4; tt++) {
                short8 b = FRAG(wreg, tt * 4 + kc, lane);
                accL[tt] = __builtin_amdgcn_mfma_f32_16x16x32_bf16(a4[kc], b, accL[tt], 0, 0, 0);
            }
        }
        __syncthreads();
    }

    // L0 epilogue -> h in own-wave band (stride 66)
#pragma unroll
    for (int tt = 0; tt < 4; tt++) {
        int c = tt * 16 + n16;
        float bias = meb0[c];
#pragma unroll
        for (int r4 = 0; r4 < 4; r4++)
            hw[(quad * 4 + r4) * 66 + c] = f2bf(fmaxf(accL[tt][r4] + bias, 0.f));
    }

    // ---- edge MLP layer 1: [64x64]x[64->128] ----
    stage_frags<8, 2, 64>(w1T, wreg, t, 0);
    __syncthreads();
    {
        float4_ acc[8];
#pragma unroll
        for (int q = 0; q < 8; q++) acc[q] = (float4_){0.f, 0.f, 0.f, 0.f};
#pragma unroll
        for (int kc = 0; kc < 2; kc++) {
            short8 a = *(const short8*)&hw[n16 * 66 + kc * 32 + quad * 8];
#pragma unroll
            for (int tt = 0; tt < 8; tt++) {
                short8 b = FRAG(wreg, tt * 2 + kc, lane);
                acc[tt] = __builtin_amdgcn_mfma_f32_16x16x32_bf16(a, b, acc[tt], 0, 0, 0);
            }
        }
        // epilogue: efn into own-wave band (stride 130) + global ef store
#pragma unroll
        for (int tt = 0; tt < 8; tt++) {
            int c = tt * 16 + n16;
            float bias = meb1[c];
#pragma unroll
            for (int r4 = 0; r4 < 4; r4++) {
                int row = quad * 4 + r4;
                unsigned short v = f2bf(fmaxf(acc[tt][r4] + bias, 0.f));
                hw[row * 130 + c] = v;
                int e = e0 + w * 16 + row;
                if (e < E) ef_bf[(size_t)e * ED + c] = v;
            }
        }
    }
    __syncthreads();

    if (wmsg) {
        // ---- node-message MLP: [64x384]x[384->128], K in 6 chunks of 64 ----
        float4_ accM[8];
#pragma unroll
        for (int q = 0; q < 8; q++) accM[q] = (float4_){0.f, 0.f, 0.f, 0.f};
#pragma unroll
        for (int j = 0; j < 6; j++) {
            short8 a2[2];
#pragma unroll
            for (int kc = 0; kc < 2; kc++) {
                int kk = j * 2 + kc;
                if (kk < 8) a2[kc] = *(const short8*)(pA[kk >> 2] + (kk & 3) * 32);
                else        a2[kc] = *(const short8*)&hw[n16 * 130 + (kk - 8) * 32 + quad * 8];
            }
            stage_frags<8, 2, 384>(wmT, wreg, t, j * 64);
            __syncthreads();
#pragma unroll
            for (int kc = 0; kc < 2; kc++) {
#pragma unroll
                for (int tt = 0; tt < 8; tt++) {
                    short8 b = FRAG(wreg, tt * 2 + kc, lane);
                    accM[tt] = __builtin_amdgcn_mfma_f32_16x16x32_bf16(a2[kc], b, accM[tt], 0, 0, 0);
                }
            }
            __syncthreads();
        }

        // ---- fused aggregation ----
#pragma unroll
        for (int tt = 0; tt < 8; tt++) {
            int c = tt * 16 + n16;
            float bias = mnb0[c];
#pragma unroll
            for (int r4 = 0; r4 < 4; r4++) {
                int row = w * 16 + quad * 4 + r4;
                wreg[row * 128 + c] = f2bf(fmaxf(accM[tt][r4] + bias, 0.f));
            }
        }
        int* tg = (int*)&hef[0][0];
        if (t < 66) {
            int p = e0 - 1 + t;
            tg[t] = (p >= 0 && p < E) ? tgtp[p] : -1;
        }
        __syncthreads();
        {
            int c = t & 127, half = t >> 7;
            int r0 = half * 32;
            float acc = 0.f;
            int rs = 0;
            for (int r = 0; r < 32; r++) {
                int p = e0 + r0 + r;
                if (p >= E) break;
                int n = tg[r0 + r + 1];
                acc += bf2f(wreg[(r0 + r) * 128 + c]);
                bool end_here = (tg[r0 + r + 2] != n);
                if (end_here) {
                    bool beg_in = (rs > 0) || (tg[r0] != n);
                    if (beg_in) nf_out[(size_t)n * ND + c] = f2bf(acc);
                    else        atomicAdd(&nfx[(size_t)n * ND + c], acc);
                    acc = 0.f; rs = r + 1;
                } else if (r == 31) {
                    atomicAdd(&nfx[(size_t)n * ND + c], acc);
                }
            }
        }
    } else {
        // ---- FUSED CLASSIFY (last step): each wave classifies its 16 edges.
        // hw holds efn rows [16][stride 130]. Entirely intra-wave (DS ops of a
        // wave are ordered; no barriers needed).
        // C0: h0 = relu(ef @ cw0 + cb0)   [16 x 64]
        float4_ accC[4];
#pragma unroll
        for (int q = 0; q < 4; q++) accC[q] = (float4_){0.f, 0.f, 0.f, 0.f};
#pragma unroll
        for (int kc = 0; kc < 4; kc++) {
            short8 a = *(const short8*)&hw[n16 * 130 + kc * 32 + quad * 8];
#pragma unroll
            for (int tt = 0; tt < 4; tt++) {
                short8 b = *(const short8*)&cw0T[(size_t)(tt * 16 + n16) * 128 + kc * 32 + quad * 8];
                accC[tt] = __builtin_amdgcn_mfma_f32_16x16x32_bf16(a, b, accC[tt], 0, 0, 0);
            }
        }
#pragma unroll
        for (int tt = 0; tt < 4; tt++) {
            int c = tt * 16 + n16;
            float bias = cb0[c];
#pragma unroll
            for (int r4 = 0; r4 < 4; r4++)
                hw[(quad * 4 + r4) * 66 + c] = f2bf(fmaxf(accC[tt][r4] + bias, 0.f));
        }
        // C1: h1 = relu(h0 @ cw1 + cb1)   [16 x 32], fp32 in hw[1056..]
        float* h1w = (float*)(hw + 1056);
#pragma unroll
        for (int q = 0; q < 8; q++) {
            int idx = q * 64 + lane;
            int r = idx >> 5, c2 = idx & 31;
            float acc = cb1[c2];
#pragma unroll 8
            for (int k = 0; k < 64; k++) acc += bf2f(hw[r * 66 + k]) * cw1[k * 32 + c2];
            h1w[r * 32 + c2] = fmaxf(acc, 0.f);
        }
        // C2: out = h1 @ cw2 + cb2, scatter to original edge id
        if (lane < 16) {
            int p = e0 + w * 16 + lane;
            if (p < E) {
                float a = cb2[0];
#pragma unroll
                for (int k = 0; k < 32; k++) a += h1w[lane * 32 + k] * cw2[k];
                out[csr_eid[p]] = a;
            }
        }
    }
}

extern "C" void kernel_launch(void* const* d_in, const int* in_sizes, int n_in,
                              void* d_out, int out_size, void* d_ws, size_t ws_size,
                              hipStream_t stream)
{
    const float* x    = (const float*)d_in[0];
    const float* ea   = (const float*)d_in[1];
    const int*   eidx = (const int*)d_in[2];
    const float* new0 = (const float*)d_in[3];  const float* neb0 = (const float*)d_in[4];
    const float* new1 = (const float*)d_in[5];  const float* neb1 = (const float*)d_in[6];
    const float* eew0 = (const float*)d_in[7];  const float* eeb0 = (const float*)d_in[8];
    const float* eew1 = (const float*)d_in[9];  const float* eeb1 = (const float*)d_in[10];
    const float* mew0 = (const float*)d_in[11]; const float* meb0 = (const float*)d_in[12];
    const float* mew1 = (const float*)d_in[13]; const float* meb1 = (const float*)d_in[14];
    const float* mnw0 = (const float*)d_in[15]; const float* mnb0 = (const float*)d_in[16];
    const float* cw0  = (const float*)d_in[17]; const float* cb0  = (const float*)d_in[18];
    const float* cw1  = (const float*)d_in[19]; const float* cb1  = (const float*)d_in[20];
    const float* cw2  = (const float*)d_in[21]; const float* cb2  = (const float*)d_in[22];

    const int N = in_sizes[0] / NIN;   // 20000
    const int E = in_sizes[2] / 2;     // 100000
    const int* srcj = eidx;            // edge_index[0] = j (source)
    const int* tgti = eidx + E;        // edge_index[1] = i (target)

    char* wsb = (char*)d_ws;
    unsigned short* nf0_bf = (unsigned short*)wsb;          // N*ND
    unsigned short* nfA    = nf0_bf + (size_t)N * ND;       // N*ND (read buf)
    unsigned short* ef0_bf = nfA + (size_t)N * ND;
    unsigned short* ef_bf  = ef0_bf + (size_t)E * ED;
    unsigned short* slot   = ef_bf + (size_t)E * ED;
    unsigned short* nfB    = slot;                          // N*ND bf16 (write buf)
    float*          nfx    = (float*)(slot + (size_t)N * ND); // N*ND fp32 atomics
    unsigned short* w0T  = slot + (size_t)E * ND;           // [64][768]
    unsigned short* w1T  = w0T + 49152;                     // [128][64]
    unsigned short* wmT  = w1T + 8192;                      // [128][384]
    unsigned short* w0eT = wmT + 49152;                     // [64][KPAD]
    unsigned short* w1eT = w0eT + 64 * KPAD;                // [128][64]
    unsigned short* cw0T = w1eT + 8192;                     // [64][128]
    unsigned short* w0nT = cw0T + 8192;                     // [128][128]
    unsigned short* w1nT = w0nT + 16384;                    // [128][128]
    int* deg     = (int*)(w1nT + 16384);                    // N
    int* cursor  = deg + N;                                 // N (contiguous w/ deg)
    int* row_ptr = cursor + N;                              // N+1
    int* csr_eid = row_ptr + (N + 4);                       // E
    int* srcp    = csr_eid + E;                             // E (CSR-order source)
    int* tgtp    = srcp + E;                                // E (CSR-order target, sorted)

    const int nblocks32 = (N + TM - 1) / TM;
    const int ntiles64 = (E + 63) / 64;

    const int wprep_items = 176128 + N + (N * ND) / 4;
    wprep_k<<<(wprep_items + 255) / 256, 256, 0, stream>>>(mew0, mew1, mnw0, eew0, eew1, cw0,
                                                           new0, new1,
                                                           w0T, w1T, wmT, w0eT, w1eT, cw0T,
                                                           w0nT, w1nT, deg, nfx, N);

    // CSR build (edge_index is constant across all 4 steps)
    hist_k<<<(E + 255) / 256, 256, 0, stream>>>(tgti, deg, E);
    scan_k<<<1, 256, 0, stream>>>(deg, row_ptr, cursor, N, E);
    scatter_k<<<(E + 255) / 256, 256, 0, stream>>>(srcj, tgti, cursor, csr_eid, srcp, tgtp, E);

    // fused node+edge embed
    embed_k<<<GSE + nblocks32, 256, 0, stream>>>(ea, csr_eid, w0eT, eeb0, w1eT, eeb1,
                                                 ef0_bf, ef_bf, E, ntiles64,
                                                 x, w0nT, neb0, w1nT, neb1,
                                                 nf0_bf, nfA, N);

    unsigned short* nfR = nfA;
    unsigned short* nfW = nfB;
    for (int s = 0; s < 4; s++) {
        edge_step_k<<<ntiles64, 256, 0, stream>>>(srcp, tgtp, nf0_bf, nfR,
                                                  ef0_bf, ef_bf, nfW, nfx,
                                                  w0T, meb0, w1T, meb1, wmT, mnb0,
                                                  csr_eid, cw0T, cb0, cw1, cb1, cw2, cb2,
                                                  (float*)d_out,
                                                  E, (s < 3) ? 1 : 0);
        if (s < 3) {
            fixup_k<<<(N + 1) / 2, 256, 0, stream>>>(row_ptr, nfx, nfW, N);
            unsigned short* tmp = nfR; nfR = nfW; nfW = tmp;
        }
    }
}